// Round 2
// baseline (1007.606 us; speedup 1.0000x reference)
//
#include <hip/hip_runtime.h>
#include <math.h>

#define NPIX 131072   // 2*256*256

__device__ __forceinline__ float lrelu_f(float x) { return x >= 0.f ? x : 0.2f * x; }

// window w (0..511): b=w>>8, wi=(w>>4)&15, wj=w&15 ; l (0..255): i=l>>4, j=l&15
__device__ __forceinline__ int pix_of(int w, int l) {
    int b = w >> 8, wi = (w >> 4) & 15, wj = w & 15;
    return ((((b << 4) + wi) * 16 + (l >> 4)) << 8) + (wj << 4) + (l & 15);
}

// ---------------- prep: DynamicPosBias MLP + c2_w transpose ----------------
__device__ __forceinline__ void ln_relu15(const float* h, float* r,
                                          const float* __restrict__ g,
                                          const float* __restrict__ b) {
    float m = 0.f;
#pragma unroll
    for (int f = 0; f < 15; ++f) m += h[f];
    m *= (1.f / 15.f);
    float v = 0.f;
#pragma unroll
    for (int f = 0; f < 15; ++f) { float d = h[f] - m; v += d * d; }
    float rs = rsqrtf(v * (1.f / 15.f) + 1e-5f);
#pragma unroll
    for (int f = 0; f < 15; ++f) {
        float xx = (h[f] - m) * rs * g[f] + b[f];
        r[f] = xx > 0.f ? xx : 0.f;
    }
}

__device__ __forceinline__ void lin15(const float* r, float* h,
                                      const float* __restrict__ w,
                                      const float* __restrict__ b) {
#pragma unroll
    for (int o = 0; o < 15; ++o) {
        float s = b[o];
#pragma unroll
        for (int g = 0; g < 15; ++g) s += r[g] * w[o * 15 + g];
        h[o] = s;
    }
}

__global__ __launch_bounds__(256) void prep_pos_kernel(
    const float* __restrict__ pp_w, const float* __restrict__ pp_b,
    const float* __restrict__ ln1_g, const float* __restrict__ ln1_b,
    const float* __restrict__ p1_w, const float* __restrict__ p1_b,
    const float* __restrict__ ln2_g, const float* __restrict__ ln2_b,
    const float* __restrict__ p2_w, const float* __restrict__ p2_b,
    const float* __restrict__ ln3_g, const float* __restrict__ ln3_b,
    const float* __restrict__ p3_w, const float* __restrict__ p3_b,
    const float* __restrict__ c2_w,
    float* __restrict__ pos3, float* __restrict__ c2w_t)
{
    int tid = threadIdx.x;
    for (int idx = tid; idx < 961; idx += 256) {
        float h[15], r[15];
        float in0 = (float)(idx / 31) - 15.f;
        float in1 = (float)(idx % 31) - 15.f;
#pragma unroll
        for (int f = 0; f < 15; ++f) h[f] = in0 * pp_w[2 * f] + in1 * pp_w[2 * f + 1] + pp_b[f];
        ln_relu15(h, r, ln1_g, ln1_b);
        lin15(r, h, p1_w, p1_b);
        ln_relu15(h, r, ln2_g, ln2_b);
        lin15(r, h, p2_w, p2_b);
        ln_relu15(h, r, ln3_g, ln3_b);
#pragma unroll
        for (int o = 0; o < 6; ++o) {
            float s = p3_b[o];
#pragma unroll
            for (int g = 0; g < 15; ++g) s += r[g] * p3_w[o * 15 + g];
            pos3[idx * 6 + o] = s;
        }
    }
    // c2w_t[(ci*9+tap)*48 + co] = c2_w[(co*48+ci)*9 + tap]
    for (int idx = tid; idx < 48 * 48 * 9; idx += 256) {
        int co = idx % 48;
        int rest = idx / 48;       // ci*9 + tap
        int ci = rest / 9, tap = rest % 9;
        c2w_t[idx] = c2_w[(co * 48 + ci) * 9 + tap];
    }
}

// rpb_t[n][k][l]  (n<6, k<64 base-window key, l<256 query pos)
__global__ __launch_bounds__(256) void rpb_kernel(const float* __restrict__ pos3,
                                                  float* __restrict__ rpb_t)
{
    int out = blockIdx.x * 256 + threadIdx.x;   // < 98304
    int n = out >> 14;
    int k = (out >> 8) & 63;
    int l = out & 255;
    int a = k >> 3, c = k & 7;
    int i1 = l >> 4, j1 = l & 15;
    float s = 0.f;
#pragma unroll
    for (int bb = 0; bb < 2; ++bb)
#pragma unroll
        for (int d = 0; d < 2; ++d) {
            int i2 = a * 2 + bb, j2 = c * 2 + d;
            int rpi = (i1 - i2 + 15) * 31 + (j1 - j2 + 15);
            s += pos3[rpi * 6 + n];
        }
    rpb_t[out] = s * 0.25f;
}

// ---------------- NT GEMM v1 pieces (used by conv1): TM=8 TN=4 ----------------
__device__ __forceinline__ void stage_nt(const float* __restrict__ A, int lda, int mbase,
                                         const float* __restrict__ W, int ldw, int nbase, int nrows,
                                         int k0, float* As, float* Ws, int tid)
{
    {
        int r = tid >> 1;
        int kb = (tid & 1) * 8;
        const float* ap = A + (size_t)(mbase + r) * lda + (k0 + kb);
        float4 a0 = *(const float4*)ap;
        float4 a1 = *(const float4*)(ap + 4);
        As[(kb + 0) * 132 + r] = a0.x;  As[(kb + 1) * 132 + r] = a0.y;
        As[(kb + 2) * 132 + r] = a0.z;  As[(kb + 3) * 132 + r] = a0.w;
        As[(kb + 4) * 132 + r] = a1.x;  As[(kb + 5) * 132 + r] = a1.y;
        As[(kb + 6) * 132 + r] = a1.z;  As[(kb + 7) * 132 + r] = a1.w;
    }
    {
        int r = tid >> 2;
        int kb = (tid & 3) * 4;
        float4 wv = make_float4(0.f, 0.f, 0.f, 0.f);
        if (nbase + r < nrows)
            wv = *(const float4*)(W + (size_t)(nbase + r) * ldw + (k0 + kb));
        Ws[(kb + 0) * 68 + r] = wv.x;  Ws[(kb + 1) * 68 + r] = wv.y;
        Ws[(kb + 2) * 68 + r] = wv.z;  Ws[(kb + 3) * 68 + r] = wv.w;
    }
}

__device__ __forceinline__ void mm_nt(const float* As, const float* Ws, int ty, int tx,
                                      float acc[8][4])
{
#pragma unroll
    for (int k = 0; k < 16; ++k) {
        float4 a0 = *(const float4*)&As[k * 132 + ty * 8];
        float4 a1 = *(const float4*)&As[k * 132 + ty * 8 + 4];
        float4 w0 = *(const float4*)&Ws[k * 68 + tx * 4];
        float a[8] = {a0.x, a0.y, a0.z, a0.w, a1.x, a1.y, a1.z, a1.w};
        float wv[4] = {w0.x, w0.y, w0.z, w0.w};
#pragma unroll
        for (int i = 0; i < 8; ++i)
#pragma unroll
            for (int j = 0; j < 4; ++j) acc[i][j] += a[i] * wv[j];
    }
}

// ---------------- NT GEMM v2 pieces: BM=BN=128, TM=TN=8 ----------------
// Ws row layout: phys col = c + 4*(c>>5)  (pad every 32 floats -> 2-way max conflict)
__device__ __forceinline__ void stage_nt128(const float* __restrict__ A, int lda, int mbase,
                                            const float* __restrict__ W, int ldw, int nbase,
                                            int nrows, int k0, float* As, float* Ws, int tid)
{
    int r = tid >> 1;
    int kb = (tid & 1) * 8;
    {
        const float* ap = A + (size_t)(mbase + r) * lda + (k0 + kb);
        float4 a0 = *(const float4*)ap;
        float4 a1 = *(const float4*)(ap + 4);
        As[(kb + 0) * 132 + r] = a0.x;  As[(kb + 1) * 132 + r] = a0.y;
        As[(kb + 2) * 132 + r] = a0.z;  As[(kb + 3) * 132 + r] = a0.w;
        As[(kb + 4) * 132 + r] = a1.x;  As[(kb + 5) * 132 + r] = a1.y;
        As[(kb + 6) * 132 + r] = a1.z;  As[(kb + 7) * 132 + r] = a1.w;
    }
    {
        float4 w0 = make_float4(0.f, 0.f, 0.f, 0.f);
        float4 w1 = make_float4(0.f, 0.f, 0.f, 0.f);
        if (nbase + r < nrows) {
            const float* wp = W + (size_t)(nbase + r) * ldw + (k0 + kb);
            w0 = *(const float4*)wp;
            w1 = *(const float4*)(wp + 4);
        }
        int pr = r + 4 * (r >> 5);
        Ws[(kb + 0) * 144 + pr] = w0.x;  Ws[(kb + 1) * 144 + pr] = w0.y;
        Ws[(kb + 2) * 144 + pr] = w0.z;  Ws[(kb + 3) * 144 + pr] = w0.w;
        Ws[(kb + 4) * 144 + pr] = w1.x;  Ws[(kb + 5) * 144 + pr] = w1.y;
        Ws[(kb + 6) * 144 + pr] = w1.z;  Ws[(kb + 7) * 144 + pr] = w1.w;
    }
}

__device__ __forceinline__ void mm_nt88(const float* As, const float* Ws, int ty, int tx,
                                        float acc[8][8])
{
    int pc = tx * 8 + 4 * (tx >> 2);   // phys col of tx*8
#pragma unroll
    for (int k = 0; k < 16; ++k) {
        float4 a0 = *(const float4*)&As[k * 132 + ty * 8];
        float4 a1 = *(const float4*)&As[k * 132 + ty * 8 + 4];
        float4 b0 = *(const float4*)&Ws[k * 144 + pc];
        float4 b1 = *(const float4*)&Ws[k * 144 + pc + 4];
        float a[8] = {a0.x, a0.y, a0.z, a0.w, a1.x, a1.y, a1.z, a1.w};
        float b[8] = {b0.x, b0.y, b0.z, b0.w, b1.x, b1.y, b1.z, b1.w};
#pragma unroll
        for (int i = 0; i < 8; ++i)
#pragma unroll
            for (int j = 0; j < 8; ++j) acc[i][j] += a[i] * b[j];
    }
}

// conv1: t1 = lrelu(x @ c1_w^T + c1_b), N=48
__global__ __launch_bounds__(256) void conv1_kernel(const float* __restrict__ x,
    const float* __restrict__ w, const float* __restrict__ bias, float* __restrict__ t1)
{
    __shared__ __align__(16) float As[16 * 132];
    __shared__ __align__(16) float Ws[16 * 68];
    int tid = threadIdx.x, ty = tid >> 4, tx = tid & 15;
    int mbase = blockIdx.x * 128;
    float acc[8][4] = {};
    for (int k0 = 0; k0 < 240; k0 += 16) {
        stage_nt(x, 240, mbase, w, 240, 0, 48, k0, As, Ws, tid);
        __syncthreads();
        mm_nt(As, Ws, ty, tx, acc);
        __syncthreads();
    }
    int n = tx * 4;
    if (n < 48) {
        float4 bv = *(const float4*)(bias + n);
#pragma unroll
        for (int i = 0; i < 8; ++i) {
            size_t m = (size_t)mbase + ty * 8 + i;
            float4 o;
            o.x = lrelu_f(acc[i][0] + bv.x);
            o.y = lrelu_f(acc[i][1] + bv.y);
            o.z = lrelu_f(acc[i][2] + bv.z);
            o.w = lrelu_f(acc[i][3] + bv.w);
            *(float4*)(t1 + m * 48 + n) = o;
        }
    }
}

// conv2: 3x3 NHWC, 48->48, +bias, lrelu.  16x16 pixel tile + halo in LDS.
__global__ __launch_bounds__(256) void conv2_kernel(const float* __restrict__ t1,
    const float* __restrict__ w_t, const float* __restrict__ bias, float* __restrict__ t2)
{
    __shared__ float in_s[18 * 18 * 49];
    int bid = blockIdx.x;
    int b = bid >> 8;
    int tr = (bid >> 4) & 15, tc = bid & 15;
    int tid = threadIdx.x;
    for (int idx = tid; idx < 15552; idx += 256) {
        int row = idx / 864;
        int rem = idx - row * 864;
        int col = rem / 48;
        int ci = rem - col * 48;
        int gr = tr * 16 + row - 1;
        int gc = tc * 16 + col - 1;
        float v = 0.f;
        if (gr >= 0 && gr < 256 && gc >= 0 && gc < 256)
            v = t1[(((size_t)b << 16) + (size_t)gr * 256 + gc) * 48 + ci];
        in_s[(row * 18 + col) * 49 + ci] = v;
    }
    __syncthreads();
    int pr = tid >> 4, pc = tid & 15;
    float acc[48];
#pragma unroll
    for (int co = 0; co < 48; ++co) acc[co] = bias[co];
    for (int ci = 0; ci < 48; ++ci) {
        float xv[9];
#pragma unroll
        for (int t = 0; t < 9; ++t) {
            int dy = t / 3, dx = t % 3;
            xv[t] = in_s[((pr + dy) * 18 + (pc + dx)) * 49 + ci];
        }
#pragma unroll
        for (int t = 0; t < 9; ++t) {
            const float* wp = w_t + (ci * 9 + t) * 48;
#pragma unroll
            for (int co = 0; co < 48; ++co) acc[co] += xv[t] * wp[co];
        }
    }
    size_t opix = ((size_t)b << 16) + (size_t)(tr * 16 + pr) * 256 + (tc * 16 + pc);
    float* op = t2 + opix * 48;
#pragma unroll
    for (int c4 = 0; c4 < 12; ++c4) {
        float4 o;
        o.x = lrelu_f(acc[c4 * 4 + 0]);
        o.y = lrelu_f(acc[c4 * 4 + 1]);
        o.z = lrelu_f(acc[c4 * 4 + 2]);
        o.w = lrelu_f(acc[c4 * 4 + 3]);
        *(float4*)(op + c4 * 4) = o;
    }
}

// qv = (t2 @ c3_w^T + c3_b) * (x @ lin_w^T + lin_b)   BM=BN=128
__global__ __launch_bounds__(256) void qv_kernel(const float* __restrict__ x,
    const float* __restrict__ lin_w, const float* __restrict__ lin_b,
    const float* __restrict__ t2, const float* __restrict__ c3_w,
    const float* __restrict__ c3_b, float* __restrict__ qv)
{
    __shared__ __align__(16) float As[16 * 132];
    __shared__ __align__(16) float Ws[16 * 144];
    int tid = threadIdx.x, ty = tid >> 4, tx = tid & 15;
    int mbase = blockIdx.x * 128;
    int nbase = blockIdx.y * 128;
    float acc1[8][8] = {};
    float acc2[8][8] = {};
    for (int k0 = 0; k0 < 240; k0 += 16) {
        stage_nt128(x, 240, mbase, lin_w, 240, nbase, 240, k0, As, Ws, tid);
        __syncthreads();
        mm_nt88(As, Ws, ty, tx, acc1);
        __syncthreads();
    }
    for (int k0 = 0; k0 < 48; k0 += 16) {
        stage_nt128(t2, 48, mbase, c3_w, 48, nbase, 240, k0, As, Ws, tid);
        __syncthreads();
        mm_nt88(As, Ws, ty, tx, acc2);
        __syncthreads();
    }
    int n = nbase + tx * 8;
    if (n < 240) {   // n multiple of 8, 240 multiple of 8 -> full 8 cols in-bounds
        float4 lb0 = *(const float4*)(lin_b + n);
        float4 lb1 = *(const float4*)(lin_b + n + 4);
        float4 cb0 = *(const float4*)(c3_b + n);
        float4 cb1 = *(const float4*)(c3_b + n + 4);
#pragma unroll
        for (int i = 0; i < 8; ++i) {
            size_t m = (size_t)mbase + ty * 8 + i;
            float4 o0, o1;
            o0.x = (acc2[i][0] + cb0.x) * (acc1[i][0] + lb0.x);
            o0.y = (acc2[i][1] + cb0.y) * (acc1[i][1] + lb0.y);
            o0.z = (acc2[i][2] + cb0.z) * (acc1[i][2] + lb0.z);
            o0.w = (acc2[i][3] + cb0.w) * (acc1[i][3] + lb0.w);
            o1.x = (acc2[i][4] + cb1.x) * (acc1[i][4] + lb1.x);
            o1.y = (acc2[i][5] + cb1.y) * (acc1[i][5] + lb1.y);
            o1.z = (acc2[i][6] + cb1.z) * (acc1[i][6] + lb1.z);
            o1.w = (acc2[i][7] + cb1.w) * (acc1[i][7] + lb1.w);
            *(float4*)(qv + m * 240 + n) = o0;
            *(float4*)(qv + m * 240 + n + 4) = o1;
        }
    }
}

// spatial correlation: per (window, head).  writes cat channels [n*20, n*20+20)
__global__ __launch_bounds__(256) void xs_kernel(const float* __restrict__ qv,
    const float* __restrict__ rpb_t, const float* __restrict__ sl_w,
    const float* __restrict__ sl_b, float* __restrict__ cat)
{
    __shared__ __align__(16) float v_s[256 * 20];
    __shared__ __align__(16) float vs_s[64 * 20];
    int bid = blockIdx.x;
    int n = bid % 6;
    int w = bid / 6;
    int tid = threadIdx.x;
    int l = tid;
    size_t pix = (size_t)pix_of(w, l);
    const float* qp = qv + pix * 240 + n * 20;
    float qr[20];
#pragma unroll
    for (int h4 = 0; h4 < 5; ++h4) {
        *(float4*)&qr[h4 * 4] = *(const float4*)(qp + h4 * 4);          // q -> regs
        *(float4*)&v_s[l * 20 + h4 * 4] = *(const float4*)(qp + 120 + h4 * 4);
    }
    __syncthreads();
    float slw0 = sl_w[0], slw1 = sl_w[1], slw2 = sl_w[2], slw3 = sl_w[3];
    float slb = sl_b[0];
    for (int idx = tid; idx < 1280; idx += 256) {
        int k = idx / 20, hd = idx % 20;
        int a = k >> 3, c = k & 7;
        int l00 = a * 32 + c * 2;     // (a*2)*16 + c*2
        float vsum = slb
                   + slw0 * v_s[(l00 + 0) * 20 + hd]
                   + slw1 * v_s[(l00 + 1) * 20 + hd]
                   + slw2 * v_s[(l00 + 16) * 20 + hd]
                   + slw3 * v_s[(l00 + 17) * 20 + hd];
        vs_s[idx] = vsum;             // idx == k*20+hd
    }
    __syncthreads();
    float acc[20];
#pragma unroll
    for (int hd = 0; hd < 20; ++hd) acc[hd] = 0.f;
    const float* rp = rpb_t + (size_t)n * 16384 + l;
    for (int k = 0; k < 64; ++k) {
        float vr[20];
#pragma unroll
        for (int h4 = 0; h4 < 5; ++h4)
            *(float4*)&vr[h4 * 4] = *(const float4*)&vs_s[k * 20 + h4 * 4];
        float s0 = 0.f, s1 = 0.f, s2 = 0.f, s3 = 0.f;
#pragma unroll
        for (int hd = 0; hd < 20; hd += 4) {
            s0 += qr[hd + 0] * vr[hd + 0];
            s1 += qr[hd + 1] * vr[hd + 1];
            s2 += qr[hd + 2] * vr[hd + 2];
            s3 += qr[hd + 3] * vr[hd + 3];
        }
        float cc = (s0 + s1 + s2 + s3) * (1.f / 20.f) + rp[(size_t)k * 256];
#pragma unroll
        for (int hd = 0; hd < 20; ++hd) acc[hd] += cc * vr[hd];
    }
    float* op = cat + pix * 240 + n * 20;
#pragma unroll
    for (int h4 = 0; h4 < 5; ++h4) {
        float4 o;
        o.x = acc[h4 * 4 + 0]; o.y = acc[h4 * 4 + 1];
        o.z = acc[h4 * 4 + 2]; o.w = acc[h4 * 4 + 3];
        *(float4*)(op + h4 * 4) = o;
    }
}

// channel correlation phase 1: G[w][d][c] = sum_l vc[l,d]*qc[l,c]   (K=256)
__global__ __launch_bounds__(256) void corrc_kernel(const float* __restrict__ qv,
                                                    float* __restrict__ G)
{
    __shared__ __align__(16) float vc_s[16 * 124];
    __shared__ __align__(16) float qc_s[16 * 124];
    int w = blockIdx.x;
    int tid = threadIdx.x, ty = tid >> 4, tx = tid & 15;
    float acc[8][8] = {};
    for (int l0 = 0; l0 < 256; l0 += 16) {
        for (int idx = tid; idx < 480; idx += 256) {
            int k = idx / 30, c4 = idx % 30;
            size_t pix = (size_t)pix_of(w, l0 + k);
            const float* qp = qv + pix * 240;
            *(float4*)&qc_s[k * 124 + c4 * 4] = *(const float4*)(qp + c4 * 4);
            *(float4*)&vc_s[k * 124 + c4 * 4] = *(const float4*)(qp + 120 + c4 * 4);
        }
        __syncthreads();
#pragma unroll
        for (int k = 0; k < 16; ++k) {
            float4 a0 = *(const float4*)&vc_s[k * 124 + ty * 8];
            float4 a1 = *(const float4*)&vc_s[k * 124 + ty * 8 + 4];
            float4 b0 = *(const float4*)&qc_s[k * 124 + tx * 8];
            float4 b1 = *(const float4*)&qc_s[k * 124 + tx * 8 + 4];
            float av[8] = {a0.x, a0.y, a0.z, a0.w, a1.x, a1.y, a1.z, a1.w};
            float bv[8] = {b0.x, b0.y, b0.z, b0.w, b1.x, b1.y, b1.z, b1.w};
#pragma unroll
            for (int i = 0; i < 8; ++i)
#pragma unroll
                for (int j = 0; j < 8; ++j) acc[i][j] += av[i] * bv[j];
        }
        __syncthreads();
    }
    float* gp = G + (size_t)w * 14400;
#pragma unroll
    for (int i = 0; i < 8; ++i) {
        int d = ty * 8 + i;
        if (d < 120) {
#pragma unroll
            for (int j4 = 0; j4 < 2; ++j4) {
                int c = tx * 8 + j4 * 4;
                if (c < 120) {
                    float4 o;
                    o.x = acc[i][j4 * 4 + 0]; o.y = acc[i][j4 * 4 + 1];
                    o.z = acc[i][j4 * 4 + 2]; o.w = acc[i][j4 * 4 + 3];
                    *(float4*)(gp + (size_t)d * 120 + c) = o;
                }
            }
        }
    }
}

// channel correlation phase 2: x_c[l,c] = (1/256) sum_d vc[l,d]*G[d,c]
__global__ __launch_bounds__(256) void xc_kernel(const float* __restrict__ qv,
    const float* __restrict__ G, float* __restrict__ cat)
{
    __shared__ __align__(16) float a_s[8 * 132];
    __shared__ __align__(16) float b_s[8 * 124];
    int bid = blockIdx.x;
    int w = bid >> 1, mh = bid & 1;
    int tid = threadIdx.x, ty = tid >> 4, tx = tid & 15;
    const float* gp = G + (size_t)w * 14400;
    float acc[8][8] = {};
    for (int k0 = 0; k0 < 120; k0 += 8) {
        {
            int lloc = tid >> 1;
            int kk = (tid & 1) * 4;
            int l = mh * 128 + lloc;
            size_t pix = (size_t)pix_of(w, l);
            float4 v = *(const float4*)(qv + pix * 240 + 120 + k0 + kk);
            a_s[(kk + 0) * 132 + lloc] = v.x;
            a_s[(kk + 1) * 132 + lloc] = v.y;
            a_s[(kk + 2) * 132 + lloc] = v.z;
            a_s[(kk + 3) * 132 + lloc] = v.w;
        }
        if (tid < 240) {
            int k = tid / 30, c4 = tid % 30;
            *(float4*)&b_s[k * 124 + c4 * 4] =
                *(const float4*)(gp + (size_t)(k0 + k) * 120 + c4 * 4);
        }
        __syncthreads();
#pragma unroll
        for (int k = 0; k < 8; ++k) {
            float4 a0 = *(const float4*)&a_s[k * 132 + ty * 8];
            float4 a1 = *(const float4*)&a_s[k * 132 + ty * 8 + 4];
            float4 b0 = *(const float4*)&b_s[k * 124 + tx * 8];
            float4 b1 = *(const float4*)&b_s[k * 124 + tx * 8 + 4];
            float av[8] = {a0.x, a0.y, a0.z, a0.w, a1.x, a1.y, a1.z, a1.w};
            float bv[8] = {b0.x, b0.y, b0.z, b0.w, b1.x, b1.y, b1.z, b1.w};
#pragma unroll
            for (int i = 0; i < 8; ++i)
#pragma unroll
                for (int j = 0; j < 8; ++j) acc[i][j] += av[i] * bv[j];
        }
        __syncthreads();
    }
#pragma unroll
    for (int i = 0; i < 8; ++i) {
        int l = mh * 128 + ty * 8 + i;
        size_t pix = (size_t)pix_of(w, l);
        float* op = cat + pix * 240 + 120;
#pragma unroll
        for (int j4 = 0; j4 < 2; ++j4) {
            int c = tx * 8 + j4 * 4;
            if (c < 120) {
                float4 o;
                o.x = acc[i][j4 * 4 + 0] * (1.f / 256.f);
                o.y = acc[i][j4 * 4 + 1] * (1.f / 256.f);
                o.z = acc[i][j4 * 4 + 2] * (1.f / 256.f);
                o.w = acc[i][j4 * 4 + 3] * (1.f / 256.f);
                *(float4*)(op + c) = o;
            }
        }
    }
}

// proj: out = cat @ proj_w^T + proj_b   BM=BN=128
__global__ __launch_bounds__(256) void proj_kernel(const float* __restrict__ cat,
    const float* __restrict__ w, const float* __restrict__ bias, float* __restrict__ out)
{
    __shared__ __align__(16) float As[16 * 132];
    __shared__ __align__(16) float Ws[16 * 144];
    int tid = threadIdx.x, ty = tid >> 4, tx = tid & 15;
    int mbase = blockIdx.x * 128;
    int nbase = blockIdx.y * 128;
    float acc[8][8] = {};
    for (int k0 = 0; k0 < 240; k0 += 16) {
        stage_nt128(cat, 240, mbase, w, 240, nbase, 240, k0, As, Ws, tid);
        __syncthreads();
        mm_nt88(As, Ws, ty, tx, acc);
        __syncthreads();
    }
    int n = nbase + tx * 8;
    if (n < 240) {
        float4 b0 = *(const float4*)(bias + n);
        float4 b1 = *(const float4*)(bias + n + 4);
#pragma unroll
        for (int i = 0; i < 8; ++i) {
            size_t m = (size_t)mbase + ty * 8 + i;
            float4 o0, o1;
            o0.x = acc[i][0] + b0.x;  o0.y = acc[i][1] + b0.y;
            o0.z = acc[i][2] + b0.z;  o0.w = acc[i][3] + b0.w;
            o1.x = acc[i][4] + b1.x;  o1.y = acc[i][5] + b1.y;
            o1.z = acc[i][6] + b1.z;  o1.w = acc[i][7] + b1.w;
            *(float4*)(out + m * 240 + n) = o0;
            *(float4*)(out + m * 240 + n + 4) = o1;
        }
    }
}

extern "C" void kernel_launch(void* const* d_in, const int* in_sizes, int n_in,
                              void* d_out, int out_size, void* d_ws, size_t ws_size,
                              hipStream_t stream)
{
    (void)in_sizes; (void)n_in; (void)out_size;
    const float* x     = (const float*)d_in[0];
    const float* c1_w  = (const float*)d_in[1];
    const float* c1_b  = (const float*)d_in[2];
    const float* c2_w  = (const float*)d_in[3];
    const float* c2_b  = (const float*)d_in[4];
    const float* c3_w  = (const float*)d_in[5];
    const float* c3_b  = (const float*)d_in[6];
    const float* lin_w = (const float*)d_in[7];
    const float* lin_b = (const float*)d_in[8];
    const float* sl_w  = (const float*)d_in[9];
    const float* sl_b  = (const float*)d_in[10];
    const float* pp_w  = (const float*)d_in[11];
    const float* pp_b  = (const float*)d_in[12];
    const float* ln1_g = (const float*)d_in[13];
    const float* ln1_b = (const float*)d_in[14];
    const float* p1_w  = (const float*)d_in[15];
    const float* p1_b  = (const float*)d_in[16];
    const float* ln2_g = (const float*)d_in[17];
    const float* ln2_b = (const float*)d_in[18];
    const float* p2_w  = (const float*)d_in[19];
    const float* p2_b  = (const float*)d_in[20];
    const float* ln3_g = (const float*)d_in[21];
    const float* ln3_b = (const float*)d_in[22];
    const float* p3_w  = (const float*)d_in[23];
    const float* p3_b  = (const float*)d_in[24];
    const float* proj_w = (const float*)d_in[25];
    const float* proj_b = (const float*)d_in[26];

    float* ws = (float*)d_ws;
    // workspace layout (floats)
    float* pos3  = ws;                     // 5766
    float* rpb_t = ws + 8192;              // 98304
    float* c2w_t = ws + 106496;            // 20736
    float* t1    = ws + 127232;            // 6291456
    float* t2    = t1 + 6291456;           // 6291456 (ends 12710144)
    float* G     = t1;                     // 7372800 — overlays t1/t2 (dead after qv)
    float* qvb   = ws + 12710144;          // 31457280
    float* cat   = ws + 44167424;          // 31457280 (ends 75624704)
    const size_t required = (size_t)75624704 * 4;
    if (ws_size < required) return;        // clean fail instead of corrupting memory

    prep_pos_kernel<<<1, 256, 0, stream>>>(pp_w, pp_b, ln1_g, ln1_b, p1_w, p1_b,
                                           ln2_g, ln2_b, p2_w, p2_b, ln3_g, ln3_b,
                                           p3_w, p3_b, c2_w, pos3, c2w_t);
    rpb_kernel<<<384, 256, 0, stream>>>(pos3, rpb_t);
    conv1_kernel<<<1024, 256, 0, stream>>>(x, c1_w, c1_b, t1);
    conv2_kernel<<<512, 256, 0, stream>>>(t1, c2w_t, c2_b, t2);
    qv_kernel<<<dim3(1024, 2), 256, 0, stream>>>(x, lin_w, lin_b, t2, c3_w, c3_b, qvb);
    xs_kernel<<<3072, 256, 0, stream>>>(qvb, rpb_t, sl_w, sl_b, cat);
    corrc_kernel<<<512, 256, 0, stream>>>(qvb, G);
    xc_kernel<<<1024, 256, 0, stream>>>(qvb, G, cat);
    proj_kernel<<<dim3(1024, 2), 256, 0, stream>>>(cat, proj_w, proj_b, (float*)d_out);
}

// Round 3
// 701.265 us; speedup vs baseline: 1.4368x; 1.4368x over previous
//
#include <hip/hip_runtime.h>
#include <math.h>

#define NPIX 131072   // 2*256*256

typedef __attribute__((ext_vector_type(8))) short bfrag;
typedef __attribute__((ext_vector_type(4))) float facc;

__device__ __forceinline__ float lrelu_f(float x) { return x >= 0.f ? x : 0.2f * x; }

// window w (0..511): b=w>>8, wi=(w>>4)&15, wj=w&15 ; l (0..255): i=l>>4, j=l&15
__device__ __forceinline__ int pix_of(int w, int l) {
    int b = w >> 8, wi = (w >> 4) & 15, wj = w & 15;
    return ((((b << 4) + wi) * 16 + (l >> 4)) << 8) + (wj << 4) + (l & 15);
}

// ---- bf16 split helpers (round-to-nearest-even) ----
__device__ __forceinline__ unsigned short bf16rn(float f) {
    unsigned u = __builtin_bit_cast(unsigned, f);
    u += 0x7FFFu + ((u >> 16) & 1u);
    return (unsigned short)(u >> 16);
}
__device__ __forceinline__ float bf16tof(unsigned short h) {
    unsigned u = ((unsigned)h) << 16;
    return __builtin_bit_cast(float, u);
}

// ---------------- prep: DynamicPosBias MLP + c2_w transpose ----------------
__device__ __forceinline__ void ln_relu15(const float* h, float* r,
                                          const float* __restrict__ g,
                                          const float* __restrict__ b) {
    float m = 0.f;
#pragma unroll
    for (int f = 0; f < 15; ++f) m += h[f];
    m *= (1.f / 15.f);
    float v = 0.f;
#pragma unroll
    for (int f = 0; f < 15; ++f) { float d = h[f] - m; v += d * d; }
    float rs = rsqrtf(v * (1.f / 15.f) + 1e-5f);
#pragma unroll
    for (int f = 0; f < 15; ++f) {
        float xx = (h[f] - m) * rs * g[f] + b[f];
        r[f] = xx > 0.f ? xx : 0.f;
    }
}

__device__ __forceinline__ void lin15(const float* r, float* h,
                                      const float* __restrict__ w,
                                      const float* __restrict__ b) {
#pragma unroll
    for (int o = 0; o < 15; ++o) {
        float s = b[o];
#pragma unroll
        for (int g = 0; g < 15; ++g) s += r[g] * w[o * 15 + g];
        h[o] = s;
    }
}

__global__ __launch_bounds__(256) void prep_pos_kernel(
    const float* __restrict__ pp_w, const float* __restrict__ pp_b,
    const float* __restrict__ ln1_g, const float* __restrict__ ln1_b,
    const float* __restrict__ p1_w, const float* __restrict__ p1_b,
    const float* __restrict__ ln2_g, const float* __restrict__ ln2_b,
    const float* __restrict__ p2_w, const float* __restrict__ p2_b,
    const float* __restrict__ ln3_g, const float* __restrict__ ln3_b,
    const float* __restrict__ p3_w, const float* __restrict__ p3_b,
    const float* __restrict__ c2_w,
    float* __restrict__ pos3, float* __restrict__ c2w_t)
{
    int tid = threadIdx.x;
    for (int idx = tid; idx < 961; idx += 256) {
        float h[15], r[15];
        float in0 = (float)(idx / 31) - 15.f;
        float in1 = (float)(idx % 31) - 15.f;
#pragma unroll
        for (int f = 0; f < 15; ++f) h[f] = in0 * pp_w[2 * f] + in1 * pp_w[2 * f + 1] + pp_b[f];
        ln_relu15(h, r, ln1_g, ln1_b);
        lin15(r, h, p1_w, p1_b);
        ln_relu15(h, r, ln2_g, ln2_b);
        lin15(r, h, p2_w, p2_b);
        ln_relu15(h, r, ln3_g, ln3_b);
#pragma unroll
        for (int o = 0; o < 6; ++o) {
            float s = p3_b[o];
#pragma unroll
            for (int g = 0; g < 15; ++g) s += r[g] * p3_w[o * 15 + g];
            pos3[idx * 6 + o] = s;
        }
    }
    // c2w_t[(ci*9+tap)*48 + co] = c2_w[(co*48+ci)*9 + tap]
    for (int idx = tid; idx < 48 * 48 * 9; idx += 256) {
        int co = idx % 48;
        int rest = idx / 48;       // ci*9 + tap
        int ci = rest / 9, tap = rest % 9;
        c2w_t[idx] = c2_w[(co * 48 + ci) * 9 + tap];
    }
}

// rpb_t[n][k][l]  (n<6, k<64 base-window key, l<256 query pos)
__global__ __launch_bounds__(256) void rpb_kernel(const float* __restrict__ pos3,
                                                  float* __restrict__ rpb_t)
{
    int out = blockIdx.x * 256 + threadIdx.x;   // < 98304
    int n = out >> 14;
    int k = (out >> 8) & 63;
    int l = out & 255;
    int a = k >> 3, c = k & 7;
    int i1 = l >> 4, j1 = l & 15;
    float s = 0.f;
#pragma unroll
    for (int bb = 0; bb < 2; ++bb)
#pragma unroll
        for (int d = 0; d < 2; ++d) {
            int i2 = a * 2 + bb, j2 = c * 2 + d;
            int rpi = (i1 - i2 + 15) * 31 + (j1 - j2 + 15);
            s += pos3[rpi * 6 + n];
        }
    rpb_t[out] = s * 0.25f;
}

// ---------------- NT GEMM v1 pieces (used by conv1): TM=8 TN=4 ----------------
__device__ __forceinline__ void stage_nt(const float* __restrict__ A, int lda, int mbase,
                                         const float* __restrict__ W, int ldw, int nbase, int nrows,
                                         int k0, float* As, float* Ws, int tid)
{
    {
        int r = tid >> 1;
        int kb = (tid & 1) * 8;
        const float* ap = A + (size_t)(mbase + r) * lda + (k0 + kb);
        float4 a0 = *(const float4*)ap;
        float4 a1 = *(const float4*)(ap + 4);
        As[(kb + 0) * 132 + r] = a0.x;  As[(kb + 1) * 132 + r] = a0.y;
        As[(kb + 2) * 132 + r] = a0.z;  As[(kb + 3) * 132 + r] = a0.w;
        As[(kb + 4) * 132 + r] = a1.x;  As[(kb + 5) * 132 + r] = a1.y;
        As[(kb + 6) * 132 + r] = a1.z;  As[(kb + 7) * 132 + r] = a1.w;
    }
    {
        int r = tid >> 2;
        int kb = (tid & 3) * 4;
        float4 wv = make_float4(0.f, 0.f, 0.f, 0.f);
        if (nbase + r < nrows)
            wv = *(const float4*)(W + (size_t)(nbase + r) * ldw + (k0 + kb));
        Ws[(kb + 0) * 68 + r] = wv.x;  Ws[(kb + 1) * 68 + r] = wv.y;
        Ws[(kb + 2) * 68 + r] = wv.z;  Ws[(kb + 3) * 68 + r] = wv.w;
    }
}

__device__ __forceinline__ void mm_nt(const float* As, const float* Ws, int ty, int tx,
                                      float acc[8][4])
{
#pragma unroll
    for (int k = 0; k < 16; ++k) {
        float4 a0 = *(const float4*)&As[k * 132 + ty * 8];
        float4 a1 = *(const float4*)&As[k * 132 + ty * 8 + 4];
        float4 w0 = *(const float4*)&Ws[k * 68 + tx * 4];
        float a[8] = {a0.x, a0.y, a0.z, a0.w, a1.x, a1.y, a1.z, a1.w};
        float wv[4] = {w0.x, w0.y, w0.z, w0.w};
#pragma unroll
        for (int i = 0; i < 8; ++i)
#pragma unroll
            for (int j = 0; j < 4; ++j) acc[i][j] += a[i] * wv[j];
    }
}

// conv1: t1 = lrelu(x @ c1_w^T + c1_b), N=48
__global__ __launch_bounds__(256) void conv1_kernel(const float* __restrict__ x,
    const float* __restrict__ w, const float* __restrict__ bias, float* __restrict__ t1)
{
    __shared__ __align__(16) float As[16 * 132];
    __shared__ __align__(16) float Ws[16 * 68];
    int tid = threadIdx.x, ty = tid >> 4, tx = tid & 15;
    int mbase = blockIdx.x * 128;
    float acc[8][4] = {};
    for (int k0 = 0; k0 < 240; k0 += 16) {
        stage_nt(x, 240, mbase, w, 240, 0, 48, k0, As, Ws, tid);
        __syncthreads();
        mm_nt(As, Ws, ty, tx, acc);
        __syncthreads();
    }
    int n = tx * 4;
    if (n < 48) {
        float4 bv = *(const float4*)(bias + n);
#pragma unroll
        for (int i = 0; i < 8; ++i) {
            size_t m = (size_t)mbase + ty * 8 + i;
            float4 o;
            o.x = lrelu_f(acc[i][0] + bv.x);
            o.y = lrelu_f(acc[i][1] + bv.y);
            o.z = lrelu_f(acc[i][2] + bv.z);
            o.w = lrelu_f(acc[i][3] + bv.w);
            *(float4*)(t1 + m * 48 + n) = o;
        }
    }
}

// conv2: 3x3 NHWC, 48->48, +bias, lrelu.  16x16 pixel tile + halo in LDS.
__global__ __launch_bounds__(256) void conv2_kernel(const float* __restrict__ t1,
    const float* __restrict__ w_t, const float* __restrict__ bias, float* __restrict__ t2)
{
    __shared__ float in_s[18 * 18 * 49];
    int bid = blockIdx.x;
    int b = bid >> 8;
    int tr = (bid >> 4) & 15, tc = bid & 15;
    int tid = threadIdx.x;
    for (int idx = tid; idx < 15552; idx += 256) {
        int row = idx / 864;
        int rem = idx - row * 864;
        int col = rem / 48;
        int ci = rem - col * 48;
        int gr = tr * 16 + row - 1;
        int gc = tc * 16 + col - 1;
        float v = 0.f;
        if (gr >= 0 && gr < 256 && gc >= 0 && gc < 256)
            v = t1[(((size_t)b << 16) + (size_t)gr * 256 + gc) * 48 + ci];
        in_s[(row * 18 + col) * 49 + ci] = v;
    }
    __syncthreads();
    int pr = tid >> 4, pc = tid & 15;
    float acc[48];
#pragma unroll
    for (int co = 0; co < 48; ++co) acc[co] = bias[co];
    for (int ci = 0; ci < 48; ++ci) {
        float xv[9];
#pragma unroll
        for (int t = 0; t < 9; ++t) {
            int dy = t / 3, dx = t % 3;
            xv[t] = in_s[((pr + dy) * 18 + (pc + dx)) * 49 + ci];
        }
#pragma unroll
        for (int t = 0; t < 9; ++t) {
            const float* wp = w_t + (ci * 9 + t) * 48;
#pragma unroll
            for (int co = 0; co < 48; ++co) acc[co] += xv[t] * wp[co];
        }
    }
    size_t opix = ((size_t)b << 16) + (size_t)(tr * 16 + pr) * 256 + (tc * 16 + pc);
    float* op = t2 + opix * 48;
#pragma unroll
    for (int c4 = 0; c4 < 12; ++c4) {
        float4 o;
        o.x = lrelu_f(acc[c4 * 4 + 0]);
        o.y = lrelu_f(acc[c4 * 4 + 1]);
        o.z = lrelu_f(acc[c4 * 4 + 2]);
        o.w = lrelu_f(acc[c4 * 4 + 3]);
        *(float4*)(op + c4 * 4) = o;
    }
}

// ---------------- MFMA split-bf16 NT GEMM pieces ----------------
// LDS row layout: 8 chunks of 8 bf16 (16B): chunks 0-3 = hi k-chunks, 4-7 = lo.
// Row stride 72 shorts (144 B). Frag read: lane l -> row (l&15), chunk (l>>4).

__device__ __forceinline__ void stage_a_split(const float* __restrict__ A, int lda, int K,
                                              int mbase, int k0, short* lds_a, int tid)
{
    int r = tid >> 1;
    int kk = (tid & 1) * 16;
    const float* ap = A + (size_t)(mbase + r) * lda + (k0 + kk);
    float v[16];
#pragma unroll
    for (int j4 = 0; j4 < 4; ++j4) {
        int k = k0 + kk + j4 * 4;
        float4 t = make_float4(0.f, 0.f, 0.f, 0.f);
        if (k + 4 <= K) t = *(const float4*)(ap + j4 * 4);
        v[j4 * 4 + 0] = t.x; v[j4 * 4 + 1] = t.y;
        v[j4 * 4 + 2] = t.z; v[j4 * 4 + 3] = t.w;
    }
    bfrag hi0, hi1, lo0, lo1;
#pragma unroll
    for (int e = 0; e < 8; ++e) {
        unsigned short h = bf16rn(v[e]);
        hi0[e] = (short)h;
        lo0[e] = (short)bf16rn(v[e] - bf16tof(h));
    }
#pragma unroll
    for (int e = 0; e < 8; ++e) {
        unsigned short h = bf16rn(v[8 + e]);
        hi1[e] = (short)h;
        lo1[e] = (short)bf16rn(v[8 + e] - bf16tof(h));
    }
    short* base = lds_a + r * 72 + (tid & 1) * 16;
    *(bfrag*)(base)      = hi0;
    *(bfrag*)(base + 8)  = hi1;
    *(bfrag*)(base + 32) = lo0;
    *(bfrag*)(base + 40) = lo1;
}

__device__ __forceinline__ void stage_w_split(const float* __restrict__ W, int ldw,
                                              int nrows, int K, int nbase, int k0,
                                              short* lds_w, int tid)
{
    int r = tid >> 2;
    int kk = (tid & 3) * 8;
    int row = nbase + r;
    float v[8];
#pragma unroll
    for (int e = 0; e < 8; ++e) v[e] = 0.f;
    if (row < nrows) {
        const float* wp = W + (size_t)row * ldw + (k0 + kk);
#pragma unroll
        for (int j4 = 0; j4 < 2; ++j4) {
            int k = k0 + kk + j4 * 4;
            if (k + 4 <= K) {
                float4 t = *(const float4*)(wp + j4 * 4);
                v[j4 * 4 + 0] = t.x; v[j4 * 4 + 1] = t.y;
                v[j4 * 4 + 2] = t.z; v[j4 * 4 + 3] = t.w;
            }
        }
    }
    bfrag hi, lo;
#pragma unroll
    for (int e = 0; e < 8; ++e) {
        unsigned short h = bf16rn(v[e]);
        hi[e] = (short)h;
        lo[e] = (short)bf16rn(v[e] - bf16tof(h));
    }
    short* base = lds_w + r * 72 + (tid & 3) * 8;
    *(bfrag*)(base)      = hi;
    *(bfrag*)(base + 32) = lo;
}

// one K-pass: acc[4][2] += A[128,K] x W[240,K]^T tile (split bf16, 3 MFMAs/unit)
__device__ __forceinline__ void mfma_kpass(const float* __restrict__ A, int lda, int K,
                                           const float* __restrict__ W, int ldw,
                                           int mbase, int nbase,
                                           short* lds_a, short* lds_w,
                                           int tid, int wm, int wn, int lane,
                                           facc acc[4][2])
{
    int i = lane & 15, g = lane >> 4;
    for (int k0 = 0; k0 < K; k0 += 32) {
        stage_a_split(A, lda, K, mbase, k0, lds_a, tid);
        stage_w_split(W, ldw, 240, K, nbase, k0, lds_w, tid);
        __syncthreads();
        bfrag ah[4], al[4], bh[2], bl[2];
#pragma unroll
        for (int mu = 0; mu < 4; ++mu) {
            const short* p = lds_a + (wm * 64 + mu * 16 + i) * 72 + g * 8;
            ah[mu] = *(const bfrag*)(p);
            al[mu] = *(const bfrag*)(p + 32);
        }
#pragma unroll
        for (int nu = 0; nu < 2; ++nu) {
            const short* p = lds_w + (wn * 32 + nu * 16 + i) * 72 + g * 8;
            bh[nu] = *(const bfrag*)(p);
            bl[nu] = *(const bfrag*)(p + 32);
        }
#pragma unroll
        for (int mu = 0; mu < 4; ++mu)
#pragma unroll
            for (int nu = 0; nu < 2; ++nu) {
                acc[mu][nu] = __builtin_amdgcn_mfma_f32_16x16x32_bf16(ah[mu], bh[nu], acc[mu][nu], 0, 0, 0);
                acc[mu][nu] = __builtin_amdgcn_mfma_f32_16x16x32_bf16(ah[mu], bl[nu], acc[mu][nu], 0, 0, 0);
                acc[mu][nu] = __builtin_amdgcn_mfma_f32_16x16x32_bf16(al[mu], bh[nu], acc[mu][nu], 0, 0, 0);
            }
        __syncthreads();
    }
}

// qv = (t2 @ c3_w^T + c3_b) * (x @ lin_w^T + lin_b)   [MFMA split-bf16]
__global__ __launch_bounds__(256) void qv_mfma_kernel(const float* __restrict__ x,
    const float* __restrict__ lin_w, const float* __restrict__ lin_b,
    const float* __restrict__ t2, const float* __restrict__ c3_w,
    const float* __restrict__ c3_b, float* __restrict__ qv)
{
    __shared__ __align__(16) short lds_a[128 * 72];
    __shared__ __align__(16) short lds_w[64 * 72];
    int tid = threadIdx.x;
    int lane = tid & 63, wid = tid >> 6;
    int wm = wid >> 1, wn = wid & 1;
    int nbase = blockIdx.x * 64;
    int mbase = blockIdx.y * 128;
    facc zero = {0.f, 0.f, 0.f, 0.f};
    facc acc1[4][2], acc2[4][2];
#pragma unroll
    for (int mu = 0; mu < 4; ++mu)
#pragma unroll
        for (int nu = 0; nu < 2; ++nu) { acc1[mu][nu] = zero; acc2[mu][nu] = zero; }

    mfma_kpass(x, 240, 240, lin_w, 240, mbase, nbase, lds_a, lds_w, tid, wm, wn, lane, acc1);
    mfma_kpass(t2, 48, 48, c3_w, 48, mbase, nbase, lds_a, lds_w, tid, wm, wn, lane, acc2);

    int i = lane & 15, g = lane >> 4;
#pragma unroll
    for (int nu = 0; nu < 2; ++nu) {
        int n = nbase + wn * 32 + nu * 16 + i;
        if (n < 240) {
            float lb = lin_b[n], cb = c3_b[n];
#pragma unroll
            for (int mu = 0; mu < 4; ++mu) {
#pragma unroll
                for (int r = 0; r < 4; ++r) {
                    size_t m = (size_t)mbase + wm * 64 + mu * 16 + g * 4 + r;
                    qv[m * 240 + n] = (acc2[mu][nu][r] + cb) * (acc1[mu][nu][r] + lb);
                }
            }
        }
    }
}

// proj: out = cat @ proj_w^T + proj_b   [MFMA split-bf16]
__global__ __launch_bounds__(256) void proj_mfma_kernel(const float* __restrict__ cat,
    const float* __restrict__ w, const float* __restrict__ bias, float* __restrict__ out)
{
    __shared__ __align__(16) short lds_a[128 * 72];
    __shared__ __align__(16) short lds_w[64 * 72];
    int tid = threadIdx.x;
    int lane = tid & 63, wid = tid >> 6;
    int wm = wid >> 1, wn = wid & 1;
    int nbase = blockIdx.x * 64;
    int mbase = blockIdx.y * 128;
    facc zero = {0.f, 0.f, 0.f, 0.f};
    facc acc[4][2];
#pragma unroll
    for (int mu = 0; mu < 4; ++mu)
#pragma unroll
        for (int nu = 0; nu < 2; ++nu) acc[mu][nu] = zero;

    mfma_kpass(cat, 240, 240, w, 240, mbase, nbase, lds_a, lds_w, tid, wm, wn, lane, acc);

    int i = lane & 15, g = lane >> 4;
#pragma unroll
    for (int nu = 0; nu < 2; ++nu) {
        int n = nbase + wn * 32 + nu * 16 + i;
        if (n < 240) {
            float bv = bias[n];
#pragma unroll
            for (int mu = 0; mu < 4; ++mu) {
#pragma unroll
                for (int r = 0; r < 4; ++r) {
                    size_t m = (size_t)mbase + wm * 64 + mu * 16 + g * 4 + r;
                    out[m * 240 + n] = acc[mu][nu][r] + bv;
                }
            }
        }
    }
}

// spatial correlation: per (window, head).  writes cat channels [n*20, n*20+20)
__global__ __launch_bounds__(256) void xs_kernel(const float* __restrict__ qv,
    const float* __restrict__ rpb_t, const float* __restrict__ sl_w,
    const float* __restrict__ sl_b, float* __restrict__ cat)
{
    __shared__ __align__(16) float v_s[256 * 20];
    __shared__ __align__(16) float vs_s[64 * 20];
    int bid = blockIdx.x;
    int n = bid % 6;
    int w = bid / 6;
    int tid = threadIdx.x;
    int l = tid;
    size_t pix = (size_t)pix_of(w, l);
    const float* qp = qv + pix * 240 + n * 20;
    float qr[20];
#pragma unroll
    for (int h4 = 0; h4 < 5; ++h4) {
        *(float4*)&qr[h4 * 4] = *(const float4*)(qp + h4 * 4);          // q -> regs
        *(float4*)&v_s[l * 20 + h4 * 4] = *(const float4*)(qp + 120 + h4 * 4);
    }
    __syncthreads();
    float slw0 = sl_w[0], slw1 = sl_w[1], slw2 = sl_w[2], slw3 = sl_w[3];
    float slb = sl_b[0];
    for (int idx = tid; idx < 1280; idx += 256) {
        int k = idx / 20, hd = idx % 20;
        int a = k >> 3, c = k & 7;
        int l00 = a * 32 + c * 2;     // (a*2)*16 + c*2
        float vsum = slb
                   + slw0 * v_s[(l00 + 0) * 20 + hd]
                   + slw1 * v_s[(l00 + 1) * 20 + hd]
                   + slw2 * v_s[(l00 + 16) * 20 + hd]
                   + slw3 * v_s[(l00 + 17) * 20 + hd];
        vs_s[idx] = vsum;             // idx == k*20+hd
    }
    __syncthreads();
    float acc[20];
#pragma unroll
    for (int hd = 0; hd < 20; ++hd) acc[hd] = 0.f;
    const float* rp = rpb_t + (size_t)n * 16384 + l;
    for (int k = 0; k < 64; ++k) {
        float vr[20];
#pragma unroll
        for (int h4 = 0; h4 < 5; ++h4)
            *(float4*)&vr[h4 * 4] = *(const float4*)&vs_s[k * 20 + h4 * 4];
        float s0 = 0.f, s1 = 0.f, s2 = 0.f, s3 = 0.f;
#pragma unroll
        for (int hd = 0; hd < 20; hd += 4) {
            s0 += qr[hd + 0] * vr[hd + 0];
            s1 += qr[hd + 1] * vr[hd + 1];
            s2 += qr[hd + 2] * vr[hd + 2];
            s3 += qr[hd + 3] * vr[hd + 3];
        }
        float cc = (s0 + s1 + s2 + s3) * (1.f / 20.f) + rp[(size_t)k * 256];
#pragma unroll
        for (int hd = 0; hd < 20; ++hd) acc[hd] += cc * vr[hd];
    }
    float* op = cat + pix * 240 + n * 20;
#pragma unroll
    for (int h4 = 0; h4 < 5; ++h4) {
        float4 o;
        o.x = acc[h4 * 4 + 0]; o.y = acc[h4 * 4 + 1];
        o.z = acc[h4 * 4 + 2]; o.w = acc[h4 * 4 + 3];
        *(float4*)(op + h4 * 4) = o;
    }
}

// channel correlation phase 1: G[w][d][c] = sum_l vc[l,d]*qc[l,c]   (K=256)
__global__ __launch_bounds__(256) void corrc_kernel(const float* __restrict__ qv,
                                                    float* __restrict__ G)
{
    __shared__ __align__(16) float vc_s[16 * 124];
    __shared__ __align__(16) float qc_s[16 * 124];
    int w = blockIdx.x;
    int tid = threadIdx.x, ty = tid >> 4, tx = tid & 15;
    float acc[8][8] = {};
    for (int l0 = 0; l0 < 256; l0 += 16) {
        for (int idx = tid; idx < 480; idx += 256) {
            int k = idx / 30, c4 = idx % 30;
            size_t pix = (size_t)pix_of(w, l0 + k);
            const float* qp = qv + pix * 240;
            *(float4*)&qc_s[k * 124 + c4 * 4] = *(const float4*)(qp + c4 * 4);
            *(float4*)&vc_s[k * 124 + c4 * 4] = *(const float4*)(qp + 120 + c4 * 4);
        }
        __syncthreads();
#pragma unroll
        for (int k = 0; k < 16; ++k) {
            float4 a0 = *(const float4*)&vc_s[k * 124 + ty * 8];
            float4 a1 = *(const float4*)&vc_s[k * 124 + ty * 8 + 4];
            float4 b0 = *(const float4*)&qc_s[k * 124 + tx * 8];
            float4 b1 = *(const float4*)&qc_s[k * 124 + tx * 8 + 4];
            float av[8] = {a0.x, a0.y, a0.z, a0.w, a1.x, a1.y, a1.z, a1.w};
            float bv[8] = {b0.x, b0.y, b0.z, b0.w, b1.x, b1.y, b1.z, b1.w};
#pragma unroll
            for (int i = 0; i < 8; ++i)
#pragma unroll
                for (int j = 0; j < 8; ++j) acc[i][j] += av[i] * bv[j];
        }
        __syncthreads();
    }
    float* gp = G + (size_t)w * 14400;
#pragma unroll
    for (int i = 0; i < 8; ++i) {
        int d = ty * 8 + i;
        if (d < 120) {
#pragma unroll
            for (int j4 = 0; j4 < 2; ++j4) {
                int c = tx * 8 + j4 * 4;
                if (c < 120) {
                    float4 o;
                    o.x = acc[i][j4 * 4 + 0]; o.y = acc[i][j4 * 4 + 1];
                    o.z = acc[i][j4 * 4 + 2]; o.w = acc[i][j4 * 4 + 3];
                    *(float4*)(gp + (size_t)d * 120 + c) = o;
                }
            }
        }
    }
}

// channel correlation phase 2: x_c[l,c] = (1/256) sum_d vc[l,d]*G[d,c]
__global__ __launch_bounds__(256) void xc_kernel(const float* __restrict__ qv,
    const float* __restrict__ G, float* __restrict__ cat)
{
    __shared__ __align__(16) float a_s[8 * 132];
    __shared__ __align__(16) float b_s[8 * 124];
    int bid = blockIdx.x;
    int w = bid >> 1, mh = bid & 1;
    int tid = threadIdx.x, ty = tid >> 4, tx = tid & 15;
    const float* gp = G + (size_t)w * 14400;
    float acc[8][8] = {};
    for (int k0 = 0; k0 < 120; k0 += 8) {
        {
            int lloc = tid >> 1;
            int kk = (tid & 1) * 4;
            int l = mh * 128 + lloc;
            size_t pix = (size_t)pix_of(w, l);
            float4 v = *(const float4*)(qv + pix * 240 + 120 + k0 + kk);
            a_s[(kk + 0) * 132 + lloc] = v.x;
            a_s[(kk + 1) * 132 + lloc] = v.y;
            a_s[(kk + 2) * 132 + lloc] = v.z;
            a_s[(kk + 3) * 132 + lloc] = v.w;
        }
        if (tid < 240) {
            int k = tid / 30, c4 = tid % 30;
            *(float4*)&b_s[k * 124 + c4 * 4] =
                *(const float4*)(gp + (size_t)(k0 + k) * 120 + c4 * 4);
        }
        __syncthreads();
#pragma unroll
        for (int k = 0; k < 8; ++k) {
            float4 a0 = *(const float4*)&a_s[k * 132 + ty * 8];
            float4 a1 = *(const float4*)&a_s[k * 132 + ty * 8 + 4];
            float4 b0 = *(const float4*)&b_s[k * 124 + tx * 8];
            float4 b1 = *(const float4*)&b_s[k * 124 + tx * 8 + 4];
            float av[8] = {a0.x, a0.y, a0.z, a0.w, a1.x, a1.y, a1.z, a1.w};
            float bv[8] = {b0.x, b0.y, b0.z, b0.w, b1.x, b1.y, b1.z, b1.w};
#pragma unroll
            for (int i = 0; i < 8; ++i)
#pragma unroll
                for (int j = 0; j < 8; ++j) acc[i][j] += av[i] * bv[j];
        }
        __syncthreads();
    }
#pragma unroll
    for (int i = 0; i < 8; ++i) {
        int l = mh * 128 + ty * 8 + i;
        size_t pix = (size_t)pix_of(w, l);
        float* op = cat + pix * 240 + 120;
#pragma unroll
        for (int j4 = 0; j4 < 2; ++j4) {
            int c = tx * 8 + j4 * 4;
            if (c < 120) {
                float4 o;
                o.x = acc[i][j4 * 4 + 0] * (1.f / 256.f);
                o.y = acc[i][j4 * 4 + 1] * (1.f / 256.f);
                o.z = acc[i][j4 * 4 + 2] * (1.f / 256.f);
                o.w = acc[i][j4 * 4 + 3] * (1.f / 256.f);
                *(float4*)(op + c) = o;
            }
        }
    }
}

extern "C" void kernel_launch(void* const* d_in, const int* in_sizes, int n_in,
                              void* d_out, int out_size, void* d_ws, size_t ws_size,
                              hipStream_t stream)
{
    (void)in_sizes; (void)n_in; (void)out_size;
    const float* x     = (const float*)d_in[0];
    const float* c1_w  = (const float*)d_in[1];
    const float* c1_b  = (const float*)d_in[2];
    const float* c2_w  = (const float*)d_in[3];
    const float* c2_b  = (const float*)d_in[4];
    const float* c3_w  = (const float*)d_in[5];
    const float* c3_b  = (const float*)d_in[6];
    const float* lin_w = (const float*)d_in[7];
    const float* lin_b = (const float*)d_in[8];
    const float* sl_w  = (const float*)d_in[9];
    const float* sl_b  = (const float*)d_in[10];
    const float* pp_w  = (const float*)d_in[11];
    const float* pp_b  = (const float*)d_in[12];
    const float* ln1_g = (const float*)d_in[13];
    const float* ln1_b = (const float*)d_in[14];
    const float* p1_w  = (const float*)d_in[15];
    const float* p1_b  = (const float*)d_in[16];
    const float* ln2_g = (const float*)d_in[17];
    const float* ln2_b = (const float*)d_in[18];
    const float* p2_w  = (const float*)d_in[19];
    const float* p2_b  = (const float*)d_in[20];
    const float* ln3_g = (const float*)d_in[21];
    const float* ln3_b = (const float*)d_in[22];
    const float* p3_w  = (const float*)d_in[23];
    const float* p3_b  = (const float*)d_in[24];
    const float* proj_w = (const float*)d_in[25];
    const float* proj_b = (const float*)d_in[26];

    float* ws = (float*)d_ws;
    // workspace layout (floats)
    float* pos3  = ws;                     // 5766
    float* rpb_t = ws + 8192;              // 98304
    float* c2w_t = ws + 106496;            // 20736
    float* t1    = ws + 127232;            // 6291456
    float* t2    = t1 + 6291456;           // 6291456 (ends 12710144)
    float* G     = t1;                     // 7372800 — overlays t1/t2 (dead after qv)
    float* qvb   = ws + 12710144;          // 31457280
    float* cat   = ws + 44167424;          // 31457280 (ends 75624704)
    const size_t required = (size_t)75624704 * 4;
    if (ws_size < required) return;        // clean fail instead of corrupting memory

    prep_pos_kernel<<<1, 256, 0, stream>>>(pp_w, pp_b, ln1_g, ln1_b, p1_w, p1_b,
                                           ln2_g, ln2_b, p2_w, p2_b, ln3_g, ln3_b,
                                           p3_w, p3_b, c2_w, pos3, c2w_t);
    rpb_kernel<<<384, 256, 0, stream>>>(pos3, rpb_t);
    conv1_kernel<<<1024, 256, 0, stream>>>(x, c1_w, c1_b, t1);
    conv2_kernel<<<512, 256, 0, stream>>>(t1, c2w_t, c2_b, t2);
    qv_mfma_kernel<<<dim3(4, 1024), 256, 0, stream>>>(x, lin_w, lin_b, t2, c3_w, c3_b, qvb);
    xs_kernel<<<3072, 256, 0, stream>>>(qvb, rpb_t, sl_w, sl_b, cat);
    corrc_kernel<<<512, 256, 0, stream>>>(qvb, G);
    xc_kernel<<<1024, 256, 0, stream>>>(qvb, G, cat);
    proj_mfma_kernel<<<dim3(4, 1024), 256, 0, stream>>>(cat, proj_w, proj_b, (float*)d_out);
}